// Round 1
// baseline (131.803 us; speedup 1.0000x reference)
//
#include <hip/hip_runtime.h>

typedef short short8 __attribute__((ext_vector_type(8)));
typedef float floatx4 __attribute__((ext_vector_type(4)));

#define INF 4096

// fp32 -> bf16 with round-to-nearest-even (inputs are finite; no NaN handling needed)
__device__ __forceinline__ ushort f2bf(float f) {
  unsigned u = __builtin_bit_cast(unsigned, f);
  u += 0x7fffu + ((u >> 16) & 1u);
  return (ushort)(u >> 16);
}

// Block-diagonal GEMM: per k-block, C[M=16384, 256] = X_k[M, 256] * W_k[256,256]^T + b_k
// Tile: BM=64 rows x BN=256 cols (full block), BK=64, double-buffered LDS (80KB -> 2 WG/CU).
// 256 threads = 4 waves; wave wc computes 64 rows x cols [wc*64, wc*64+64) as 4x4 16x16x32 MFMA frags.
__global__ __launch_bounds__(256, 2) void bd_gemm(
    const float* __restrict__ x, const float* __restrict__ W,
    const float* __restrict__ bias, float* __restrict__ out)
{
  // per buffer: A = 64x64 bf16 (4096 ushort), B = 256x64 bf16 (16384 ushort)
  __shared__ ushort lds[2 * 20480];

  const int bid = blockIdx.x;
  // XCD-chunked swizzle (4096 WGs, 8 XCDs, 512/XCD): each XCD covers 2 k-blocks -> W_k L2-resident
  const int swz = (bid & 7) * 512 + (bid >> 3);
  const int kblk = swz >> 8;   // 0..15
  const int mt   = swz & 255;  // 0..255 m-tiles of 64 rows
  const int tid  = threadIdx.x;
  const int lane = tid & 63;
  const int wc   = tid >> 6;   // wave -> output column quadrant

  const float* xb = x + (size_t)mt * 64 * INF + kblk * 256;
  const float* wb = W + (size_t)kblk * 256 * 256;

  floatx4 fa[2][2];  // A staging: 2 chunks x 8 floats
  floatx4 fb[8][2];  // B staging: 8 chunks x 8 floats
  floatx4 acc[4][4];
#pragma unroll
  for (int i = 0; i < 4; ++i)
#pragma unroll
    for (int j = 0; j < 4; ++j)
#pragma unroll
      for (int e = 0; e < 4; ++e) acc[i][j][e] = 0.0f;

  // ---- staging: global fp32 -> regs ----
#define LOADA(kk)                                                    \
  _Pragma("unroll") for (int p = 0; p < 2; ++p) {                    \
    const int id = tid + p * 256;                                    \
    const int r = id >> 3, cc = id & 7;                              \
    const float* s = xb + (size_t)r * INF + (kk) * 64 + cc * 8;      \
    fa[p][0] = *(const floatx4*)s;                                   \
    fa[p][1] = *(const floatx4*)(s + 4);                             \
  }

#define LOADB(kk)                                                    \
  _Pragma("unroll") for (int p = 0; p < 8; ++p) {                    \
    const int id = tid + p * 256;                                    \
    const int r = id >> 3, cc = id & 7;                              \
    const float* s = wb + (size_t)r * 256 + (kk) * 64 + cc * 8;      \
    fb[p][0] = *(const floatx4*)s;                                   \
    fb[p][1] = *(const floatx4*)(s + 4);                             \
  }

  // ---- regs -> cvt bf16 -> LDS (XOR-swizzled 16B chunks: cc ^ (r&7)) ----
#define STORE(buf)                                                           \
  _Pragma("unroll") for (int p = 0; p < 2; ++p) {                            \
    const int id = tid + p * 256;                                            \
    const int r = id >> 3, cc = id & 7;                                      \
    short8 u;                                                                \
    _Pragma("unroll") for (int j = 0; j < 4; ++j) {                          \
      u[j] = (short)f2bf(fa[p][0][j]);                                       \
      u[4 + j] = (short)f2bf(fa[p][1][j]);                                   \
    }                                                                        \
    *(short8*)&lds[(buf) * 20480 + r * 64 + ((cc ^ (r & 7)) << 3)] = u;      \
  }                                                                          \
  _Pragma("unroll") for (int p = 0; p < 8; ++p) {                            \
    const int id = tid + p * 256;                                            \
    const int r = id >> 3, cc = id & 7;                                      \
    short8 u;                                                                \
    _Pragma("unroll") for (int j = 0; j < 4; ++j) {                          \
      u[j] = (short)f2bf(fb[p][0][j]);                                       \
      u[4 + j] = (short)f2bf(fb[p][1][j]);                                   \
    }                                                                        \
    *(short8*)&lds[(buf) * 20480 + 4096 + r * 64 + ((cc ^ (r & 7)) << 3)] = u; \
  }

  // ---- LDS -> frags -> MFMA ----
#define COMPUTE(buf)                                                         \
  _Pragma("unroll") for (int ks = 0; ks < 2; ++ks) {                         \
    const int ko = ks * 32 + ((lane >> 4) << 3);                             \
    const int cc = ko >> 3;                                                  \
    short8 afr[4], bfr[4];                                                   \
    _Pragma("unroll") for (int mi = 0; mi < 4; ++mi) {                       \
      const int r = mi * 16 + (lane & 15);                                   \
      afr[mi] = *(const short8*)&lds[(buf) * 20480 + r * 64 + ((cc ^ (r & 7)) << 3)]; \
    }                                                                        \
    _Pragma("unroll") for (int ni = 0; ni < 4; ++ni) {                       \
      const int r = wc * 64 + ni * 16 + (lane & 15);                         \
      bfr[ni] = *(const short8*)&lds[(buf) * 20480 + 4096 + r * 64 + ((cc ^ (r & 7)) << 3)]; \
    }                                                                        \
    _Pragma("unroll") for (int mi = 0; mi < 4; ++mi)                         \
      _Pragma("unroll") for (int ni = 0; ni < 4; ++ni)                       \
        acc[mi][ni] = __builtin_amdgcn_mfma_f32_16x16x32_bf16(               \
            afr[mi], bfr[ni], acc[mi][ni], 0, 0, 0);                         \
  }

  // prologue
  LOADA(0) LOADB(0) STORE(0)
  __syncthreads();

#pragma unroll
  for (int kk = 0; kk < 4; ++kk) {
    const int cur = kk & 1;
    if (kk < 3) { LOADA(kk + 1) LOADB(kk + 1) }  // issue next-step global loads early (latency hides under MFMA)
    COMPUTE(cur)
    if (kk < 3) {
      STORE(cur ^ 1)
      __syncthreads();
    }
  }

  // epilogue: bias + store (C/D frag: col = lane&15, row = (lane>>4)*4 + j)
  const float* bp = bias + kblk * 256;
  float bv[4];
#pragma unroll
  for (int ni = 0; ni < 4; ++ni) bv[ni] = bp[wc * 64 + ni * 16 + (lane & 15)];

  float* ob = out + (size_t)mt * 64 * INF + kblk * 256;
#pragma unroll
  for (int mi = 0; mi < 4; ++mi) {
#pragma unroll
    for (int ni = 0; ni < 4; ++ni) {
      const int col = wc * 64 + ni * 16 + (lane & 15);
#pragma unroll
      for (int j = 0; j < 4; ++j) {
        const int row = mi * 16 + ((lane >> 4) << 2) + j;
        ob[(size_t)row * INF + col] = acc[mi][ni][j] + bv[ni];
      }
    }
  }

#undef LOADA
#undef LOADB
#undef STORE
#undef COMPUTE
}

extern "C" void kernel_launch(void* const* d_in, const int* in_sizes, int n_in,
                              void* d_out, int out_size, void* d_ws, size_t ws_size,
                              hipStream_t stream) {
  const float* x = (const float*)d_in[0];
  const float* W = (const float*)d_in[1];
  const float* b = (const float*)d_in[2];
  float* out = (float*)d_out;
  // 256 m-tiles (16384/64) x 16 k-blocks = 4096 workgroups
  hipLaunchKernelGGL(bd_gemm, dim3(4096), dim3(256), 0, stream, x, W, b, out);
}